// Round 9
// baseline (1778.889 us; speedup 1.0000x reference)
//
#include <hip/hip_runtime.h>
#include <hip/hip_bf16.h>

typedef __attribute__((ext_vector_type(8))) short bf16x8;
typedef __attribute__((ext_vector_type(4))) float f32x4;

static __device__ __forceinline__ unsigned short f2bf(float x) {
    __hip_bfloat16 h = __float2bfloat16(x);
    return *(unsigned short*)&h;
}
static __device__ __forceinline__ float bflo(unsigned int w) { return __uint_as_float(w << 16); }
static __device__ __forceinline__ float bfhi(unsigned int w) { return __uint_as_float(w & 0xffff0000u); }
static __device__ __forceinline__ float bf1(unsigned short u) { return __uint_as_float(((unsigned int)u) << 16); }

// ---------------- conv1 + ReLU: [512,1,28,28] -> h1n NHWC bf16 [512,20,20,256] ----------
__global__ __launch_bounds__(320) void conv1_k(const float* __restrict__ in,
                                               const float* __restrict__ w,
                                               const float* __restrict__ bias,
                                               unsigned short* __restrict__ h1n) {
    int blk = blockIdx.x;
    int b = blk >> 4;
    int c0 = (blk & 15) * 16;
    __shared__ float img[784];
    __shared__ float wl[16 * 81];
    __shared__ float bl[16];
    __shared__ unsigned short tr[20 * 328];
    int tid = threadIdx.x;
    for (int t = tid; t < 784; t += 320) img[t] = in[b * 784 + t];
    for (int t = tid; t < 1296; t += 320) wl[t] = w[c0 * 81 + t];
    if (tid < 16) bl[tid] = bias[c0 + tid];
    __syncthreads();

    int co = tid / 20, oy = tid % 20;
    float wr[81];
#pragma unroll
    for (int k = 0; k < 81; k++) wr[k] = wl[co * 81 + k];
    float acc[20];
    float bv = bl[co];
#pragma unroll
    for (int ox = 0; ox < 20; ox++) acc[ox] = bv;

#pragma unroll
    for (int ky = 0; ky < 9; ky++) {
        const float* rp = &img[(oy + ky) * 28];
        float r[28];
#pragma unroll
        for (int v = 0; v < 7; v++) {
            float4 t4 = ((const float4*)rp)[v];
            r[v * 4 + 0] = t4.x; r[v * 4 + 1] = t4.y;
            r[v * 4 + 2] = t4.z; r[v * 4 + 3] = t4.w;
        }
#pragma unroll
        for (int kx = 0; kx < 9; kx++) {
            float wv = wr[ky * 9 + kx];
#pragma unroll
            for (int ox = 0; ox < 20; ox++) acc[ox] += r[ox + kx] * wv;
        }
    }
#pragma unroll
    for (int ox = 0; ox < 20; ox++)
        tr[oy * 328 + ox * 16 + co] = f2bf(fmaxf(acc[ox], 0.f));
    __syncthreads();
    for (int g = tid; g < 800; g += 320) {
        int p = g >> 1, half = g & 1;
        uint4 v = *(uint4*)&tr[(p / 20) * 328 + (p % 20) * 16 + half * 8];
        *(uint4*)&h1n[(b * 400 + p) * 256 + c0 + half * 8] = v;
    }
}

// ---------------- W2 transpose (+ zero pad plane kk=81) ----------------------------------
__global__ __launch_bounds__(256) void wt2_k(const float* __restrict__ w2,
                                             unsigned short* __restrict__ Wt2) {
    int cout = blockIdx.x;
    int ci = threadIdx.x;
    const float* src = w2 + (cout * 256 + ci) * 81;
#pragma unroll 1
    for (int kk = 0; kk < 81; kk++)
        Wt2[kk * 65536 + cout * 256 + ci] = f2bf(src[kk]);
    Wt2[81 * 65536 + cout * 256 + ci] = 0;   // zero pad plane: slice-1 round 163 reads it
}

// ---------------- conv2 implicit GEMM, bf16 MFMA, split-K 2 ------------------------------
// Block tile 128x128, BK=64, 4 waves (2x2), wave tile 64x64, acc 4x4. XOR-swizzled LDS.
// grid (144, 2, 2): z = K-slice (kk 0..40 / 41..81, plane 81 zeroed). 164 rounds each.
// __launch_bounds__(256,1): VGPR budget 512 — the LDS-driven default capped at 96 and
// spilled 2.25 GB of scratch (R8 post-mortem). Do NOT raise the min-waves arg.
__global__ __launch_bounds__(256, 1) void conv2_k(const unsigned short* __restrict__ h1n,
                                                  const unsigned short* __restrict__ Wt2,
                                                  const float* __restrict__ bias,
                                                  float* __restrict__ u,
                                                  float* __restrict__ part) {
    __shared__ unsigned short sA[128 * 64];   // 16 KB
    __shared__ unsigned short sB[128 * 64];   // 16 KB
    int tid = threadIdx.x;
    int m0 = blockIdx.x * 128;
    int n0 = blockIdx.y * 128;
    int slice = blockIdx.z;
    int ks = slice * 41;

    int r = tid >> 1;
    int kcb = (tid & 1) * 4;
    int R = m0 + r;
    int b = R / 36, m = R % 36;
    int oy = m / 6, ox = m % 6;
    int abase = b * 102400 + oy * 2 * 5120 + ox * 2 * 256;
    int bbase = (n0 + r) * 256;
    int lw[4];
#pragma unroll
    for (int cc = 0; cc < 4; cc++) {
        int kc = kcb + cc;
        lw[cc] = r * 64 + 8 * (kc ^ (r & 7));
    }

    f32x4 acc[4][4];
#pragma unroll
    for (int i = 0; i < 4; i++)
#pragma unroll
        for (int j = 0; j < 4; j++) acc[i][j] = (f32x4){0.f, 0.f, 0.f, 0.f};

    int wv = tid >> 6, lane = tid & 63;
    int wm = wv >> 1, wn = wv & 1;
    int lr = lane & 15, quad = lane >> 4;

    uint4 ar[4], br[4];
    {   // preload round 0 of this slice (kk=ks, cr=0)
        int ky = ks / 9, kx = ks % 9;
        int aoff = ky * 5120 + kx * 256;
        int boff = ks * 65536;
#pragma unroll
        for (int cc = 0; cc < 4; cc++) {
            int kc = kcb + cc;
            ar[cc] = *(const uint4*)(h1n + abase + aoff + kc * 8);
            br[cc] = *(const uint4*)(Wt2 + boff + bbase + kc * 8);
        }
    }

#pragma unroll 1
    for (int rr = 0; rr < 164; rr++) {
        __syncthreads();
#pragma unroll
        for (int cc = 0; cc < 4; cc++) {
            *(uint4*)&sA[lw[cc]] = ar[cc];
            *(uint4*)&sB[lw[cc]] = br[cc];
        }
        __syncthreads();
        int nrr = rr + 1;
        if (nrr < 164) {
            int kk = ks + (nrr >> 2), cr = nrr & 3;
            int ky = kk / 9, kx = kk % 9;
            int aoff = ky * 5120 + kx * 256 + cr * 64;
            int boff = kk * 65536 + cr * 64;
#pragma unroll
            for (int cc = 0; cc < 4; cc++) {
                int kc = kcb + cc;
                ar[cc] = *(const uint4*)(h1n + abase + aoff + kc * 8);
                br[cc] = *(const uint4*)(Wt2 + boff + bbase + kc * 8);
            }
        }
#pragma unroll
        for (int s = 0; s < 2; s++) {
            bf16x8 af[4], bf[4];
#pragma unroll
            for (int i = 0; i < 4; i++) {
                int arow = wm * 64 + i * 16 + lr;
                af[i] = *(bf16x8*)&sA[arow * 64 + 8 * ((s * 4 + quad) ^ (lr & 7))];
            }
#pragma unroll
            for (int j = 0; j < 4; j++) {
                int brow = wn * 64 + j * 16 + lr;
                bf[j] = *(bf16x8*)&sB[brow * 64 + 8 * ((s * 4 + quad) ^ (lr & 7))];
            }
#pragma unroll
            for (int i = 0; i < 4; i++)
#pragma unroll
                for (int j = 0; j < 4; j++)
                    acc[i][j] = __builtin_amdgcn_mfma_f32_16x16x32_bf16(
                        af[i], bf[j], acc[i][j], 0, 0, 0);
        }
    }
    // epilogue: C/D layout col=lane&15, row=quad*4+reg
    float* dst = slice ? part : u;
#pragma unroll
    for (int j = 0; j < 4; j++) {
        int col = n0 + wn * 64 + j * 16 + lr;
        float bv = slice ? 0.f : bias[col];
#pragma unroll
        for (int i = 0; i < 4; i++) {
#pragma unroll
            for (int rg = 0; rg < 4; rg++) {
                int RR = m0 + wm * 64 + i * 16 + quad * 4 + rg;
                int bb = RR / 36, mm = RR % 36;
                int oyy = mm / 6, oxx = mm % 6;
                dst[bb * 9216 + oxx * 1536 + oyy * 256 + col] = acc[i][j][rg] + bv;
            }
        }
    }
}

// ---------------- fold split-K partials: u += part ---------------------------------------
__global__ __launch_bounds__(256) void add_k(float* __restrict__ u,
                                             const float* __restrict__ part) {
    int n = (blockIdx.x * 256 + threadIdx.x) * 4;
    float4 a = *(float4*)&u[n];
    float4 p = *(const float4*)&part[n];
    a.x += p.x; a.y += p.y; a.z += p.z; a.w += p.w;
    *(float4*)&u[n] = a;
}

// ---------------- u_hat: u[b,i,p] x W[i,j,p,q] -> uhat bf16 [b][j*16+q][i] ---------------
__global__ __launch_bounds__(256) void uhat_k(const float* __restrict__ u,
                                              const float* __restrict__ W,
                                              unsigned short* __restrict__ uhat) {
    int i0 = blockIdx.x * 64;
    int b0 = blockIdx.y * 8;
    __shared__ float ul[8 * 64 * 9];
    __shared__ float wl[64 * 129];
    int tid = threadIdx.x;

    for (int t = tid; t < 4096; t += 256) {
        int bb = t >> 9, r = t & 511;
        ul[bb * 576 + (r >> 3) * 9 + (r & 7)] = u[(b0 + bb) * 9216 + i0 * 8 + r];
    }

    int il = tid & 63, g = tid >> 6;
    for (int j = 0; j < 10; j++) {
        __syncthreads();
        for (int t = tid; t < 2048; t += 256) {
            int li = t >> 5, off = (t & 31) * 4;
            float4 v = *(const float4*)&W[(i0 + li) * 1280 + j * 128 + off];
            float* d = &wl[li * 129 + off];
            d[0] = v.x; d[1] = v.y; d[2] = v.z; d[3] = v.w;
        }
        __syncthreads();
#pragma unroll 1
        for (int bb = 0; bb < 8; bb++) {
            float ur[8];
#pragma unroll
            for (int p = 0; p < 8; p++) ur[p] = ul[bb * 576 + il * 9 + p];
#pragma unroll
            for (int k = 0; k < 4; k++) {
                int q = g * 4 + k;
                float a = 0.f;
#pragma unroll
                for (int p = 0; p < 8; p++) a += ur[p] * wl[il * 129 + p * 16 + q];
                uhat[((size_t)(b0 + bb) * 160 + j * 16 + q) * 1152 + i0 + il] = f2bf(a);
            }
        }
    }
}

// ---------------- zero s buffer ----------------------------------------------------------
__global__ __launch_bounds__(256) void zero_k(float* __restrict__ p, int n) {
    int k = blockIdx.x * 256 + threadIdx.x;
    if (k < n) p[k] = 0.f;
}

// ---------------- fused routing iteration (verified R6) ----------------------------------
template <int MODE>
__global__ __launch_bounds__(256) void routeAB_k(const unsigned short* __restrict__ uhat,
                                                 const float* __restrict__ v_in,
                                                 float* __restrict__ logits,
                                                 float* __restrict__ s_glob) {
    int chunk = blockIdx.x;
    int b = blockIdx.y;
    int tid = threadIdx.x;
    __shared__ unsigned short su[160 * 128];
    __shared__ float c_sh[10 * 128];
    __shared__ float v_sh[160];
    const unsigned short* base = uhat + (size_t)b * 184320 + chunk * 128;

#pragma unroll
    for (int rnd = 0; rnd < 10; rnd++) {
        int idx = rnd * 256 + tid;
        int row = idx >> 4, c16 = idx & 15;
        uint4 vv = *(const uint4*)(base + row * 1152 + c16 * 8);
        *(uint4*)&su[row * 128 + c16 * 8] = vv;
    }
    if (MODE > 0 && tid < 160) v_sh[tid] = v_in[b * 160 + tid];
    __syncthreads();

    if (MODE > 0) {
        int i = tid >> 1, h = tid & 1;
        int gi = chunk * 128 + i;
        float la[5];
#pragma unroll
        for (int jj = 0; jj < 5; jj++) {
            float a = 0.f;
            int jbase = (h * 5 + jj) * 16;
#pragma unroll
            for (int q = 0; q < 16; q++)
                a = fmaf(bf1(su[(jbase + q) * 128 + i]), v_sh[jbase + q], a);
            la[jj] = a;
        }
        float lg[10];
#pragma unroll
        for (int j = 0; j < 10; j++) {
            float contrib = ((j / 5) == h) ? la[j % 5] : 0.f;
            contrib += __shfl_xor(contrib, 1);
            if (MODE == 2) contrib += logits[(size_t)b * 11520 + j * 1152 + gi];
            lg[j] = contrib;
        }
        if (MODE == 1 && h == 0) {
            float* lp = logits + (size_t)b * 11520 + gi;
#pragma unroll
            for (int j = 0; j < 10; j++) lp[j * 1152] = lg[j];
        }
        float m = lg[0];
#pragma unroll
        for (int j = 1; j < 10; j++) m = fmaxf(m, lg[j]);
        float e[10], sum = 0.f;
#pragma unroll
        for (int j = 0; j < 10; j++) { e[j] = __expf(lg[j] - m); sum += e[j]; }
        float inv = 1.f / sum;
        if (h == 0) {
#pragma unroll
            for (int j = 0; j < 10; j++) c_sh[j * 128 + i] = e[j] * inv;
        }
    }
    __syncthreads();

    int wv = tid >> 6, lane = tid & 63;
#pragma unroll 1
    for (int row = wv; row < 160; row += 4) {
        unsigned int uv = *(const unsigned int*)&su[row * 128 + lane * 2];
        float x0 = bflo(uv), x1 = bfhi(uv);
        float p;
        if (MODE == 0) {
            p = (x0 + x1) * 0.1f;
        } else {
            int j = row >> 4;
            float2 cc = *(const float2*)&c_sh[j * 128 + lane * 2];
            p = fmaf(x0, cc.x, x1 * cc.y);
        }
#pragma unroll
        for (int off = 32; off; off >>= 1) p += __shfl_down(p, off);
        if (lane == 0) atomicAdd(&s_glob[b * 160 + row], p);
    }
}

// ---------------- squash: s -> v (or out), re-zero s -------------------------------------
template <int LAST>
__global__ __launch_bounds__(192) void squash_k(float* __restrict__ s_glob,
                                                float* __restrict__ v_glob,
                                                float* __restrict__ out) {
    int b = blockIdx.x, tid = threadIdx.x;
    __shared__ float s_sh[160];
    __shared__ float sc[10];
    if (tid < 160) s_sh[tid] = s_glob[b * 160 + tid];
    __syncthreads();
    if (tid < 10) {
        float sq = 0.f;
#pragma unroll
        for (int q = 0; q < 16; q++) { float x = s_sh[tid * 16 + q]; sq += x * x; }
        float norm = sqrtf(sq + 1e-8f);
        sc[tid] = (sq / (1.0f + sq)) / norm;
    }
    __syncthreads();
    if (tid < 160) {
        float v = s_sh[tid] * sc[tid >> 4];
        if (LAST) out[b * 160 + tid] = v;
        else v_glob[b * 160 + tid] = v;
        s_glob[b * 160 + tid] = 0.f;
    }
}

extern "C" void kernel_launch(void* const* d_in, const int* in_sizes, int n_in,
                              void* d_out, int out_size, void* d_ws, size_t ws_size,
                              hipStream_t stream) {
    const float* input = (const float*)d_in[0];
    const float* c1w = (const float*)d_in[1];
    const float* c1b = (const float*)d_in[2];
    const float* c2w = (const float*)d_in[3];
    const float* c2b = (const float*)d_in[4];
    const float* capW = (const float*)d_in[5];
    float* out = (float*)d_out;

    // ws layout (bytes):
    //   [0)            u fp32 [512][9216]                      18,874,368
    //   [+18874368)    s_glob fp32 [512][160]                     327,680
    //   [+19202048)    v_glob fp32 [512][160]                     327,680
    //   [+19529728)    logits fp32 [512][10][1152]             23,592,960
    //                  (aliased: conv2 split-K partials, dead before routing t1)
    //   [+43122688)    region B: {Wt2 (82 planes) + h1n} then uhat bf16 (Cr*368640)
    const size_t U_OFF = 0;
    const size_t S_OFF = 18874368;
    const size_t V_OFF = 19202048;
    const size_t L_OFF = 19529728;
    const size_t B_OFF = 43122688;
    const size_t WT2_BYTES = 82 * 65536 * 2;     // 10,747,904
    const size_t CONV_BYTES = WT2_BYTES + 104857600;
    if (ws_size < B_OFF + CONV_BYTES) return;

    char* wsb = (char*)d_ws;
    float* u_buf = (float*)(wsb + U_OFF);
    float* s_glob = (float*)(wsb + S_OFF);
    float* v_glob = (float*)(wsb + V_OFF);
    float* logits = (float*)(wsb + L_OFF);
    float* part   = (float*)(wsb + L_OFF);   // 18,874,368 B <= logits region, dead by then
    unsigned short* Wt2 = (unsigned short*)(wsb + B_OFF);
    unsigned short* h1n = (unsigned short*)(wsb + B_OFF + WT2_BYTES);
    unsigned short* uhatb = (unsigned short*)(wsb + B_OFF);

    size_t availB = ws_size - B_OFF;
    int Cr = 0;
    const int cands[7] = {512, 256, 128, 64, 32, 16, 8};
    for (int k = 0; k < 7; k++) {
        if ((size_t)cands[k] * 368640 <= availB) { Cr = cands[k]; break; }
    }
    if (Cr == 0) return;

    zero_k<<<320, 256, 0, stream>>>(s_glob, 81920);
    wt2_k<<<256, 256, 0, stream>>>(c2w, Wt2);
    conv1_k<<<512 * 16, 320, 0, stream>>>(input, c1w, c1b, h1n);
    conv2_k<<<dim3(144, 2, 2), 256, 0, stream>>>(h1n, Wt2, c2b, u_buf, part);
    add_k<<<4608, 256, 0, stream>>>(u_buf, part);

    for (int b0 = 0; b0 < 512; b0 += Cr) {
        uhat_k<<<dim3(18, Cr / 8), 256, 0, stream>>>(u_buf + (size_t)b0 * 9216, capW, uhatb);
        routeAB_k<0><<<dim3(9, Cr), 256, 0, stream>>>(uhatb, v_glob, logits, s_glob);
        squash_k<0><<<Cr, 192, 0, stream>>>(s_glob, v_glob, out);
        routeAB_k<1><<<dim3(9, Cr), 256, 0, stream>>>(uhatb, v_glob, logits, s_glob);
        squash_k<0><<<Cr, 192, 0, stream>>>(s_glob, v_glob, out);
        routeAB_k<2><<<dim3(9, Cr), 256, 0, stream>>>(uhatb, v_glob, logits, s_glob);
        squash_k<1><<<Cr, 192, 0, stream>>>(s_glob, v_glob, out + (size_t)b0 * 160);
    }
}

// Round 10
// 1008.857 us; speedup vs baseline: 1.7633x; 1.7633x over previous
//
#include <hip/hip_runtime.h>
#include <hip/hip_bf16.h>

typedef __attribute__((ext_vector_type(8))) short bf16x8;
typedef __attribute__((ext_vector_type(4))) float f32x4;

static __device__ __forceinline__ unsigned short f2bf(float x) {
    __hip_bfloat16 h = __float2bfloat16(x);
    return *(unsigned short*)&h;
}
static __device__ __forceinline__ float bflo(unsigned int w) { return __uint_as_float(w << 16); }
static __device__ __forceinline__ float bfhi(unsigned int w) { return __uint_as_float(w & 0xffff0000u); }
static __device__ __forceinline__ float bf1(unsigned short u) { return __uint_as_float(((unsigned int)u) << 16); }

// ---------------- conv1 + ReLU: [512,1,28,28] -> h1n NHWC bf16 [512,20,20,256] ----------
__global__ __launch_bounds__(320) void conv1_k(const float* __restrict__ in,
                                               const float* __restrict__ w,
                                               const float* __restrict__ bias,
                                               unsigned short* __restrict__ h1n) {
    int blk = blockIdx.x;
    int b = blk >> 4;
    int c0 = (blk & 15) * 16;
    __shared__ float img[784];
    __shared__ float wl[16 * 81];
    __shared__ float bl[16];
    __shared__ unsigned short tr[20 * 328];
    int tid = threadIdx.x;
    for (int t = tid; t < 784; t += 320) img[t] = in[b * 784 + t];
    for (int t = tid; t < 1296; t += 320) wl[t] = w[c0 * 81 + t];
    if (tid < 16) bl[tid] = bias[c0 + tid];
    __syncthreads();

    int co = tid / 20, oy = tid % 20;
    float wr[81];
#pragma unroll
    for (int k = 0; k < 81; k++) wr[k] = wl[co * 81 + k];
    float acc[20];
    float bv = bl[co];
#pragma unroll
    for (int ox = 0; ox < 20; ox++) acc[ox] = bv;

#pragma unroll
    for (int ky = 0; ky < 9; ky++) {
        const float* rp = &img[(oy + ky) * 28];
        float r[28];
#pragma unroll
        for (int v = 0; v < 7; v++) {
            float4 t4 = ((const float4*)rp)[v];
            r[v * 4 + 0] = t4.x; r[v * 4 + 1] = t4.y;
            r[v * 4 + 2] = t4.z; r[v * 4 + 3] = t4.w;
        }
#pragma unroll
        for (int kx = 0; kx < 9; kx++) {
            float wv = wr[ky * 9 + kx];
#pragma unroll
            for (int ox = 0; ox < 20; ox++) acc[ox] += r[ox + kx] * wv;
        }
    }
#pragma unroll
    for (int ox = 0; ox < 20; ox++)
        tr[oy * 328 + ox * 16 + co] = f2bf(fmaxf(acc[ox], 0.f));
    __syncthreads();
    for (int g = tid; g < 800; g += 320) {
        int p = g >> 1, half = g & 1;
        uint4 v = *(uint4*)&tr[(p / 20) * 328 + (p % 20) * 16 + half * 8];
        *(uint4*)&h1n[(b * 400 + p) * 256 + c0 + half * 8] = v;
    }
}

// ---------------- W2 transpose: w2[cout][ci][kk] fp32 -> Wt2[kk][cout][ci] bf16 ----------
__global__ __launch_bounds__(256) void wt2_k(const float* __restrict__ w2,
                                             unsigned short* __restrict__ Wt2) {
    int cout = blockIdx.x;
    int ci = threadIdx.x;
    const float* src = w2 + (cout * 256 + ci) * 81;
#pragma unroll 1
    for (int kk = 0; kk < 81; kk++)
        Wt2[kk * 65536 + cout * 256 + ci] = f2bf(src[kk]);
}

// ---------------- conv2 implicit GEMM, bf16 MFMA -----------------------------------------
// R6-verified structure (128x64 tile, direct load->LDS, VGPR ~52, 5-6 blocks/CU, no spill)
// + R9-verified XOR swizzle (chunk ^ (row&7), stride 64 shorts) -> 0 bank conflicts.
// grid (144, 4) = 576 blocks. NO register prefetch, NO launch_bounds min-waves (R8/R9
// post-mortems: both caused 2.2 GB/dispatch scratch spill at 128x128).
__global__ __launch_bounds__(256) void conv2_k(const unsigned short* __restrict__ h1n,
                                               const unsigned short* __restrict__ Wt2,
                                               const float* __restrict__ bias,
                                               float* __restrict__ u) {
    __shared__ unsigned short sA[128 * 64];   // 16 KB, XOR-swizzled
    __shared__ unsigned short sB[64 * 64];    // 8 KB, XOR-swizzled
    int tid = threadIdx.x;
    int m0 = blockIdx.x * 128;
    int n0 = blockIdx.y * 64;

    // staging: thread t -> rows rl+{0,32,64,96} (A) / rl+{0,32} (B), 16B chunk c8
    int rl = tid >> 3;
    int c8 = tid & 7;
    int abase[4];
#pragma unroll
    for (int i = 0; i < 4; i++) {
        int R = m0 + rl + i * 32;
        int b = R / 36, m = R % 36;
        int oy = m / 6, ox = m % 6;
        abase[i] = b * 102400 + oy * 2 * 5120 + ox * 2 * 256 + c8 * 8;
    }
    int bbase0 = (n0 + rl) * 256 + c8 * 8;
    int bbase1 = (n0 + rl + 32) * 256 + c8 * 8;
    int lw = rl * 64 + 8 * (c8 ^ (rl & 7));   // rows +32i keep same low-3 bits -> +i*2048

    f32x4 acc[4][2];
#pragma unroll
    for (int i = 0; i < 4; i++)
#pragma unroll
        for (int j = 0; j < 2; j++) acc[i][j] = (f32x4){0.f, 0.f, 0.f, 0.f};

    int wv = tid >> 6, lane = tid & 63;
    int wm = wv >> 1, wn = wv & 1;
    int lr = lane & 15, quad = lane >> 4;

#pragma unroll 1
    for (int kk = 0; kk < 81; kk++) {
        int ky = kk / 9, kx = kk % 9;
        int aoff = ky * 5120 + kx * 256;
        int boff = kk * 65536;
#pragma unroll 1
        for (int cr = 0; cr < 4; cr++) {
            __syncthreads();
#pragma unroll
            for (int i = 0; i < 4; i++) {
                uint4 v = *(const uint4*)(h1n + abase[i] + aoff + cr * 64);
                *(uint4*)&sA[lw + i * 2048] = v;
            }
            {
                uint4 v0 = *(const uint4*)(Wt2 + boff + bbase0 + cr * 64);
                uint4 v1 = *(const uint4*)(Wt2 + boff + bbase1 + cr * 64);
                *(uint4*)&sB[lw] = v0;
                *(uint4*)&sB[lw + 2048] = v1;
            }
            __syncthreads();
#pragma unroll
            for (int s = 0; s < 2; s++) {
                bf16x8 bf[2];
#pragma unroll
                for (int j = 0; j < 2; j++) {
                    int brow = wn * 32 + j * 16 + lr;
                    bf[j] = *(bf16x8*)&sB[brow * 64 + 8 * ((s * 4 + quad) ^ (lr & 7))];
                }
#pragma unroll
                for (int i = 0; i < 4; i++) {
                    int arow = wm * 64 + i * 16 + lr;
                    bf16x8 af = *(bf16x8*)&sA[arow * 64 + 8 * ((s * 4 + quad) ^ (lr & 7))];
#pragma unroll
                    for (int j = 0; j < 2; j++)
                        acc[i][j] = __builtin_amdgcn_mfma_f32_16x16x32_bf16(
                            af, bf[j], acc[i][j], 0, 0, 0);
                }
            }
        }
    }
    // epilogue: C/D layout col=lane&15, row=quad*4+reg
#pragma unroll
    for (int j = 0; j < 2; j++) {
        int col = n0 + wn * 32 + j * 16 + lr;
        float bv = bias[col];
#pragma unroll
        for (int i = 0; i < 4; i++) {
#pragma unroll
            for (int rg = 0; rg < 4; rg++) {
                int RR = m0 + wm * 64 + i * 16 + quad * 4 + rg;
                int bb = RR / 36, mm = RR % 36;
                int oyy = mm / 6, oxx = mm % 6;
                u[bb * 9216 + oxx * 1536 + oyy * 256 + col] = acc[i][j][rg] + bv;
            }
        }
    }
}

// ---------------- u_hat: u[b,i,p] x W[i,j,p,q] -> uhat bf16 [b][j*16+q][i] ---------------
__global__ __launch_bounds__(256) void uhat_k(const float* __restrict__ u,
                                              const float* __restrict__ W,
                                              unsigned short* __restrict__ uhat) {
    int i0 = blockIdx.x * 64;
    int b0 = blockIdx.y * 8;
    __shared__ float ul[8 * 64 * 9];
    __shared__ float wl[64 * 129];
    int tid = threadIdx.x;

    for (int t = tid; t < 4096; t += 256) {
        int bb = t >> 9, r = t & 511;
        ul[bb * 576 + (r >> 3) * 9 + (r & 7)] = u[(b0 + bb) * 9216 + i0 * 8 + r];
    }

    int il = tid & 63, g = tid >> 6;
    for (int j = 0; j < 10; j++) {
        __syncthreads();
        for (int t = tid; t < 2048; t += 256) {
            int li = t >> 5, off = (t & 31) * 4;
            float4 v = *(const float4*)&W[(i0 + li) * 1280 + j * 128 + off];
            float* d = &wl[li * 129 + off];
            d[0] = v.x; d[1] = v.y; d[2] = v.z; d[3] = v.w;
        }
        __syncthreads();
#pragma unroll 1
        for (int bb = 0; bb < 8; bb++) {
            float ur[8];
#pragma unroll
            for (int p = 0; p < 8; p++) ur[p] = ul[bb * 576 + il * 9 + p];
#pragma unroll
            for (int k = 0; k < 4; k++) {
                int q = g * 4 + k;
                float a = 0.f;
#pragma unroll
                for (int p = 0; p < 8; p++) a += ur[p] * wl[il * 129 + p * 16 + q];
                uhat[((size_t)(b0 + bb) * 160 + j * 16 + q) * 1152 + i0 + il] = f2bf(a);
            }
        }
    }
}

// ---------------- zero s buffer ----------------------------------------------------------
__global__ __launch_bounds__(256) void zero_k(float* __restrict__ p, int n) {
    int k = blockIdx.x * 256 + threadIdx.x;
    if (k < n) p[k] = 0.f;
}

// ---------------- fused routing iteration (verified R6) ----------------------------------
template <int MODE>
__global__ __launch_bounds__(256) void routeAB_k(const unsigned short* __restrict__ uhat,
                                                 const float* __restrict__ v_in,
                                                 float* __restrict__ logits,
                                                 float* __restrict__ s_glob) {
    int chunk = blockIdx.x;
    int b = blockIdx.y;
    int tid = threadIdx.x;
    __shared__ unsigned short su[160 * 128];
    __shared__ float c_sh[10 * 128];
    __shared__ float v_sh[160];
    const unsigned short* base = uhat + (size_t)b * 184320 + chunk * 128;

#pragma unroll
    for (int rnd = 0; rnd < 10; rnd++) {
        int idx = rnd * 256 + tid;
        int row = idx >> 4, c16 = idx & 15;
        uint4 vv = *(const uint4*)(base + row * 1152 + c16 * 8);
        *(uint4*)&su[row * 128 + c16 * 8] = vv;
    }
    if (MODE > 0 && tid < 160) v_sh[tid] = v_in[b * 160 + tid];
    __syncthreads();

    if (MODE > 0) {
        int i = tid >> 1, h = tid & 1;
        int gi = chunk * 128 + i;
        float la[5];
#pragma unroll
        for (int jj = 0; jj < 5; jj++) {
            float a = 0.f;
            int jbase = (h * 5 + jj) * 16;
#pragma unroll
            for (int q = 0; q < 16; q++)
                a = fmaf(bf1(su[(jbase + q) * 128 + i]), v_sh[jbase + q], a);
            la[jj] = a;
        }
        float lg[10];
#pragma unroll
        for (int j = 0; j < 10; j++) {
            float contrib = ((j / 5) == h) ? la[j % 5] : 0.f;
            contrib += __shfl_xor(contrib, 1);
            if (MODE == 2) contrib += logits[(size_t)b * 11520 + j * 1152 + gi];
            lg[j] = contrib;
        }
        if (MODE == 1 && h == 0) {
            float* lp = logits + (size_t)b * 11520 + gi;
#pragma unroll
            for (int j = 0; j < 10; j++) lp[j * 1152] = lg[j];
        }
        float m = lg[0];
#pragma unroll
        for (int j = 1; j < 10; j++) m = fmaxf(m, lg[j]);
        float e[10], sum = 0.f;
#pragma unroll
        for (int j = 0; j < 10; j++) { e[j] = __expf(lg[j] - m); sum += e[j]; }
        float inv = 1.f / sum;
        if (h == 0) {
#pragma unroll
            for (int j = 0; j < 10; j++) c_sh[j * 128 + i] = e[j] * inv;
        }
    }
    __syncthreads();

    int wv = tid >> 6, lane = tid & 63;
#pragma unroll 1
    for (int row = wv; row < 160; row += 4) {
        unsigned int uv = *(const unsigned int*)&su[row * 128 + lane * 2];
        float x0 = bflo(uv), x1 = bfhi(uv);
        float p;
        if (MODE == 0) {
            p = (x0 + x1) * 0.1f;
        } else {
            int j = row >> 4;
            float2 cc = *(const float2*)&c_sh[j * 128 + lane * 2];
            p = fmaf(x0, cc.x, x1 * cc.y);
        }
#pragma unroll
        for (int off = 32; off; off >>= 1) p += __shfl_down(p, off);
        if (lane == 0) atomicAdd(&s_glob[b * 160 + row], p);
    }
}

// ---------------- squash: s -> v (or out), re-zero s -------------------------------------
template <int LAST>
__global__ __launch_bounds__(192) void squash_k(float* __restrict__ s_glob,
                                                float* __restrict__ v_glob,
                                                float* __restrict__ out) {
    int b = blockIdx.x, tid = threadIdx.x;
    __shared__ float s_sh[160];
    __shared__ float sc[10];
    if (tid < 160) s_sh[tid] = s_glob[b * 160 + tid];
    __syncthreads();
    if (tid < 10) {
        float sq = 0.f;
#pragma unroll
        for (int q = 0; q < 16; q++) { float x = s_sh[tid * 16 + q]; sq += x * x; }
        float norm = sqrtf(sq + 1e-8f);
        sc[tid] = (sq / (1.0f + sq)) / norm;
    }
    __syncthreads();
    if (tid < 160) {
        float v = s_sh[tid] * sc[tid >> 4];
        if (LAST) out[b * 160 + tid] = v;
        else v_glob[b * 160 + tid] = v;
        s_glob[b * 160 + tid] = 0.f;
    }
}

extern "C" void kernel_launch(void* const* d_in, const int* in_sizes, int n_in,
                              void* d_out, int out_size, void* d_ws, size_t ws_size,
                              hipStream_t stream) {
    const float* input = (const float*)d_in[0];
    const float* c1w = (const float*)d_in[1];
    const float* c1b = (const float*)d_in[2];
    const float* c2w = (const float*)d_in[3];
    const float* c2b = (const float*)d_in[4];
    const float* capW = (const float*)d_in[5];
    float* out = (float*)d_out;

    // ws layout (bytes):
    //   [0)            u fp32 [512][9216]                      18,874,368
    //   [+18874368)    s_glob fp32 [512][160]                     327,680
    //   [+19202048)    v_glob fp32 [512][160]                     327,680
    //   [+19529728)    logits fp32 [512][10][1152]             23,592,960
    //   [+43122688)    region B: {Wt2 + h1n} (conv) then uhat bf16 (Cr*368640)
    const size_t U_OFF = 0;
    const size_t S_OFF = 18874368;
    const size_t V_OFF = 19202048;
    const size_t L_OFF = 19529728;
    const size_t B_OFF = 43122688;
    const size_t WT2_BYTES = 10616832;
    const size_t CONV_BYTES = WT2_BYTES + 104857600;
    if (ws_size < B_OFF + CONV_BYTES) return;

    char* wsb = (char*)d_ws;
    float* u_buf = (float*)(wsb + U_OFF);
    float* s_glob = (float*)(wsb + S_OFF);
    float* v_glob = (float*)(wsb + V_OFF);
    float* logits = (float*)(wsb + L_OFF);
    unsigned short* Wt2 = (unsigned short*)(wsb + B_OFF);
    unsigned short* h1n = (unsigned short*)(wsb + B_OFF + WT2_BYTES);
    unsigned short* uhatb = (unsigned short*)(wsb + B_OFF);

    size_t availB = ws_size - B_OFF;
    int Cr = 0;
    const int cands[7] = {512, 256, 128, 64, 32, 16, 8};
    for (int k = 0; k < 7; k++) {
        if ((size_t)cands[k] * 368640 <= availB) { Cr = cands[k]; break; }
    }
    if (Cr == 0) return;

    zero_k<<<320, 256, 0, stream>>>(s_glob, 81920);
    wt2_k<<<256, 256, 0, stream>>>(c2w, Wt2);
    conv1_k<<<512 * 16, 320, 0, stream>>>(input, c1w, c1b, h1n);
    conv2_k<<<dim3(144, 4), 256, 0, stream>>>(h1n, Wt2, c2b, u_buf);

    for (int b0 = 0; b0 < 512; b0 += Cr) {
        uhat_k<<<dim3(18, Cr / 8), 256, 0, stream>>>(u_buf + (size_t)b0 * 9216, capW, uhatb);
        routeAB_k<0><<<dim3(9, Cr), 256, 0, stream>>>(uhatb, v_glob, logits, s_glob);
        squash_k<0><<<Cr, 192, 0, stream>>>(s_glob, v_glob, out);
        routeAB_k<1><<<dim3(9, Cr), 256, 0, stream>>>(uhatb, v_glob, logits, s_glob);
        squash_k<0><<<Cr, 192, 0, stream>>>(s_glob, v_glob, out);
        routeAB_k<2><<<dim3(9, Cr), 256, 0, stream>>>(uhatb, v_glob, logits, s_glob);
        squash_k<1><<<Cr, 192, 0, stream>>>(s_glob, v_glob, out + (size_t)b0 * 160);
    }
}

// Round 11
// 995.931 us; speedup vs baseline: 1.7862x; 1.0130x over previous
//
#include <hip/hip_runtime.h>
#include <hip/hip_bf16.h>

typedef __attribute__((ext_vector_type(8))) short bf16x8;
typedef __attribute__((ext_vector_type(4))) float f32x4;

static __device__ __forceinline__ unsigned short f2bf(float x) {
    __hip_bfloat16 h = __float2bfloat16(x);
    return *(unsigned short*)&h;
}
static __device__ __forceinline__ float bflo(unsigned int w) { return __uint_as_float(w << 16); }
static __device__ __forceinline__ float bfhi(unsigned int w) { return __uint_as_float(w & 0xffff0000u); }
static __device__ __forceinline__ float bf1(unsigned short u) { return __uint_as_float(((unsigned int)u) << 16); }

#define PART_FLOATS 4718592   // 512*9216

// ---------------- conv1 + ReLU: [512,1,28,28] -> h1n NHWC bf16 [512,20,20,256] ----------
__global__ __launch_bounds__(320) void conv1_k(const float* __restrict__ in,
                                               const float* __restrict__ w,
                                               const float* __restrict__ bias,
                                               unsigned short* __restrict__ h1n) {
    int blk = blockIdx.x;
    int b = blk >> 4;
    int c0 = (blk & 15) * 16;
    __shared__ float img[784];
    __shared__ float wl[16 * 81];
    __shared__ float bl[16];
    __shared__ unsigned short tr[20 * 328];
    int tid = threadIdx.x;
    for (int t = tid; t < 784; t += 320) img[t] = in[b * 784 + t];
    for (int t = tid; t < 1296; t += 320) wl[t] = w[c0 * 81 + t];
    if (tid < 16) bl[tid] = bias[c0 + tid];
    __syncthreads();

    int co = tid / 20, oy = tid % 20;
    float wr[81];
#pragma unroll
    for (int k = 0; k < 81; k++) wr[k] = wl[co * 81 + k];
    float acc[20];
    float bv = bl[co];
#pragma unroll
    for (int ox = 0; ox < 20; ox++) acc[ox] = bv;

#pragma unroll
    for (int ky = 0; ky < 9; ky++) {
        const float* rp = &img[(oy + ky) * 28];
        float r[28];
#pragma unroll
        for (int v = 0; v < 7; v++) {
            float4 t4 = ((const float4*)rp)[v];
            r[v * 4 + 0] = t4.x; r[v * 4 + 1] = t4.y;
            r[v * 4 + 2] = t4.z; r[v * 4 + 3] = t4.w;
        }
#pragma unroll
        for (int kx = 0; kx < 9; kx++) {
            float wv = wr[ky * 9 + kx];
#pragma unroll
            for (int ox = 0; ox < 20; ox++) acc[ox] += r[ox + kx] * wv;
        }
    }
#pragma unroll
    for (int ox = 0; ox < 20; ox++)
        tr[oy * 328 + ox * 16 + co] = f2bf(fmaxf(acc[ox], 0.f));
    __syncthreads();
    for (int g = tid; g < 800; g += 320) {
        int p = g >> 1, half = g & 1;
        uint4 v = *(uint4*)&tr[(p / 20) * 328 + (p % 20) * 16 + half * 8];
        *(uint4*)&h1n[(b * 400 + p) * 256 + c0 + half * 8] = v;
    }
}

// ---------------- W2 transpose (84 kk planes; 81..83 zeroed for uniform split-K 4) -------
__global__ __launch_bounds__(256) void wt2_k(const float* __restrict__ w2,
                                             unsigned short* __restrict__ Wt2) {
    int cout = blockIdx.x;
    int ci = threadIdx.x;
    const float* src = w2 + (cout * 256 + ci) * 81;
#pragma unroll 1
    for (int kk = 0; kk < 81; kk++)
        Wt2[kk * 65536 + cout * 256 + ci] = f2bf(src[kk]);
#pragma unroll
    for (int kk = 81; kk < 84; kk++)
        Wt2[kk * 65536 + cout * 256 + ci] = 0;
}

// ---------------- conv2 implicit GEMM, bf16 MFMA, 128x128, split-K 4 ---------------------
// Direct uint4 load->LDS (R6/R10-proven, no prefetch arrays -> no spill driver),
// XOR swizzle (R9-proven, 0 conflicts). LDS padded to 36 KB: occupancy heuristic targets
// 4 blocks/CU -> VGPR cap 128 (R8/R9 post-mortem: 32 KB -> 5 blocks -> 96-cap -> spill).
// grid (144, 2, 4) = 1152 blocks; slice kk planes [21s, 21s+21), 84 rounds each.
__global__ __launch_bounds__(256) void conv2_k(const unsigned short* __restrict__ h1n,
                                               const unsigned short* __restrict__ Wt2,
                                               const float* __restrict__ bias,
                                               float* __restrict__ u,
                                               float* __restrict__ part1,
                                               float* __restrict__ part23) {
    __shared__ unsigned short sA[128 * 64];   // 16 KB, XOR-swizzled
    __shared__ unsigned short sB[128 * 64];   // 16 KB, XOR-swizzled
    __shared__ unsigned short sPad[2048];     // 4 KB occupancy shaping (see header comment)
    int tid = threadIdx.x;
    int m0 = blockIdx.x * 128;
    int n0 = blockIdx.y * 128;
    int slice = blockIdx.z;
    int ks = slice * 21;

    // staging: thread t -> row rl = t>>1 (A and B), 4 chunks starting (t&1)*4
    int rl = tid >> 1;
    int kcb = (tid & 1) * 4;
    int R = m0 + rl;
    int b = R / 36, m = R % 36;
    int oy = m / 6, ox = m % 6;
    int abase = b * 102400 + oy * 2 * 5120 + ox * 2 * 256;
    int bbase = (n0 + rl) * 256;
    int lw[4];
#pragma unroll
    for (int cc = 0; cc < 4; cc++) {
        int kc = kcb + cc;
        lw[cc] = rl * 64 + 8 * (kc ^ (rl & 7));
    }

    f32x4 acc[4][4];
#pragma unroll
    for (int i = 0; i < 4; i++)
#pragma unroll
        for (int j = 0; j < 4; j++) acc[i][j] = (f32x4){0.f, 0.f, 0.f, 0.f};

    int wv = tid >> 6, lane = tid & 63;
    int wm = wv >> 1, wn = wv & 1;
    int lr = lane & 15, quad = lane >> 4;

#pragma unroll 1
    for (int rr = 0; rr < 84; rr++) {
        int kk = ks + (rr >> 2), cr = rr & 3;
        int ky = kk / 9, kx = kk % 9;
        int aoff = ky * 5120 + kx * 256 + cr * 64;
        int boff = kk * 65536 + cr * 64;
        __syncthreads();
#pragma unroll
        for (int cc = 0; cc < 4; cc++) {
            uint4 va = *(const uint4*)(h1n + abase + aoff + (kcb + cc) * 8);
            *(uint4*)&sA[lw[cc]] = va;
        }
#pragma unroll
        for (int cc = 0; cc < 4; cc++) {
            uint4 vb = *(const uint4*)(Wt2 + boff + bbase + (kcb + cc) * 8);
            *(uint4*)&sB[lw[cc]] = vb;
        }
        __syncthreads();
#pragma unroll
        for (int s = 0; s < 2; s++) {
            bf16x8 af[4], bf[4];
#pragma unroll
            for (int i = 0; i < 4; i++) {
                int arow = wm * 64 + i * 16 + lr;
                af[i] = *(bf16x8*)&sA[arow * 64 + 8 * ((s * 4 + quad) ^ (lr & 7))];
            }
#pragma unroll
            for (int j = 0; j < 4; j++) {
                int brow = wn * 64 + j * 16 + lr;
                bf[j] = *(bf16x8*)&sB[brow * 64 + 8 * ((s * 4 + quad) ^ (lr & 7))];
            }
#pragma unroll
            for (int i = 0; i < 4; i++)
#pragma unroll
                for (int j = 0; j < 4; j++)
                    acc[i][j] = __builtin_amdgcn_mfma_f32_16x16x32_bf16(
                        af[i], bf[j], acc[i][j], 0, 0, 0);
        }
    }
    // keep sPad allocated (condition never true, but compiler can't prove it)
    if (m0 == 0x40000000) sPad[tid & 2047] = 1;

    // epilogue: C/D layout col=lane&15, row=quad*4+reg
    float* dst = (slice == 0) ? u : ((slice == 1) ? part1 : part23 + (size_t)(slice - 2) * PART_FLOATS);
#pragma unroll
    for (int j = 0; j < 4; j++) {
        int col = n0 + wn * 64 + j * 16 + lr;
        float bv = (slice == 0) ? bias[col] : 0.f;
#pragma unroll
        for (int i = 0; i < 4; i++) {
#pragma unroll
            for (int rg = 0; rg < 4; rg++) {
                int RR = m0 + wm * 64 + i * 16 + quad * 4 + rg;
                int bb = RR / 36, mm = RR % 36;
                int oyy = mm / 6, oxx = mm % 6;
                dst[bb * 9216 + oxx * 1536 + oyy * 256 + col] = acc[i][j][rg] + bv;
            }
        }
    }
}

// ---------------- fold split-K partials: u += p1 + p2 + p3 -------------------------------
__global__ __launch_bounds__(256) void add_k(float* __restrict__ u,
                                             const float* __restrict__ p1,
                                             const float* __restrict__ p23) {
    int n = (blockIdx.x * 256 + threadIdx.x) * 4;
    float4 a = *(float4*)&u[n];
    float4 x = *(const float4*)&p1[n];
    float4 y = *(const float4*)&p23[n];
    float4 z = *(const float4*)&p23[PART_FLOATS + n];
    a.x += x.x + y.x + z.x;
    a.y += x.y + y.y + z.y;
    a.z += x.z + y.z + z.z;
    a.w += x.w + y.w + z.w;
    *(float4*)&u[n] = a;
}

// ---------------- u_hat: u[b,i,p] x W[i,j,p,q] -> uhat bf16 [b][j*16+q][i] ---------------
__global__ __launch_bounds__(256) void uhat_k(const float* __restrict__ u,
                                              const float* __restrict__ W,
                                              unsigned short* __restrict__ uhat) {
    int i0 = blockIdx.x * 64;
    int b0 = blockIdx.y * 8;
    __shared__ float ul[8 * 64 * 9];
    __shared__ float wl[64 * 129];
    int tid = threadIdx.x;

    for (int t = tid; t < 4096; t += 256) {
        int bb = t >> 9, r = t & 511;
        ul[bb * 576 + (r >> 3) * 9 + (r & 7)] = u[(b0 + bb) * 9216 + i0 * 8 + r];
    }

    int il = tid & 63, g = tid >> 6;
    for (int j = 0; j < 10; j++) {
        __syncthreads();
        for (int t = tid; t < 2048; t += 256) {
            int li = t >> 5, off = (t & 31) * 4;
            float4 v = *(const float4*)&W[(i0 + li) * 1280 + j * 128 + off];
            float* d = &wl[li * 129 + off];
            d[0] = v.x; d[1] = v.y; d[2] = v.z; d[3] = v.w;
        }
        __syncthreads();
#pragma unroll 1
        for (int bb = 0; bb < 8; bb++) {
            float ur[8];
#pragma unroll
            for (int p = 0; p < 8; p++) ur[p] = ul[bb * 576 + il * 9 + p];
#pragma unroll
            for (int k = 0; k < 4; k++) {
                int q = g * 4 + k;
                float a = 0.f;
#pragma unroll
                for (int p = 0; p < 8; p++) a += ur[p] * wl[il * 129 + p * 16 + q];
                uhat[((size_t)(b0 + bb) * 160 + j * 16 + q) * 1152 + i0 + il] = f2bf(a);
            }
        }
    }
}

// ---------------- zero s buffer ----------------------------------------------------------
__global__ __launch_bounds__(256) void zero_k(float* __restrict__ p, int n) {
    int k = blockIdx.x * 256 + threadIdx.x;
    if (k < n) p[k] = 0.f;
}

// ---------------- fused routing iteration (verified R6) ----------------------------------
template <int MODE>
__global__ __launch_bounds__(256) void routeAB_k(const unsigned short* __restrict__ uhat,
                                                 const float* __restrict__ v_in,
                                                 float* __restrict__ logits,
                                                 float* __restrict__ s_glob) {
    int chunk = blockIdx.x;
    int b = blockIdx.y;
    int tid = threadIdx.x;
    __shared__ unsigned short su[160 * 128];
    __shared__ float c_sh[10 * 128];
    __shared__ float v_sh[160];
    const unsigned short* base = uhat + (size_t)b * 184320 + chunk * 128;

#pragma unroll
    for (int rnd = 0; rnd < 10; rnd++) {
        int idx = rnd * 256 + tid;
        int row = idx >> 4, c16 = idx & 15;
        uint4 vv = *(const uint4*)(base + row * 1152 + c16 * 8);
        *(uint4*)&su[row * 128 + c16 * 8] = vv;
    }
    if (MODE > 0 && tid < 160) v_sh[tid] = v_in[b * 160 + tid];
    __syncthreads();

    if (MODE > 0) {
        int i = tid >> 1, h = tid & 1;
        int gi = chunk * 128 + i;
        float la[5];
#pragma unroll
        for (int jj = 0; jj < 5; jj++) {
            float a = 0.f;
            int jbase = (h * 5 + jj) * 16;
#pragma unroll
            for (int q = 0; q < 16; q++)
                a = fmaf(bf1(su[(jbase + q) * 128 + i]), v_sh[jbase + q], a);
            la[jj] = a;
        }
        float lg[10];
#pragma unroll
        for (int j = 0; j < 10; j++) {
            float contrib = ((j / 5) == h) ? la[j % 5] : 0.f;
            contrib += __shfl_xor(contrib, 1);
            if (MODE == 2) contrib += logits[(size_t)b * 11520 + j * 1152 + gi];
            lg[j] = contrib;
        }
        if (MODE == 1 && h == 0) {
            float* lp = logits + (size_t)b * 11520 + gi;
#pragma unroll
            for (int j = 0; j < 10; j++) lp[j * 1152] = lg[j];
        }
        float m = lg[0];
#pragma unroll
        for (int j = 1; j < 10; j++) m = fmaxf(m, lg[j]);
        float e[10], sum = 0.f;
#pragma unroll
        for (int j = 0; j < 10; j++) { e[j] = __expf(lg[j] - m); sum += e[j]; }
        float inv = 1.f / sum;
        if (h == 0) {
#pragma unroll
            for (int j = 0; j < 10; j++) c_sh[j * 128 + i] = e[j] * inv;
        }
    }
    __syncthreads();

    int wv = tid >> 6, lane = tid & 63;
#pragma unroll 1
    for (int row = wv; row < 160; row += 4) {
        unsigned int uv = *(const unsigned int*)&su[row * 128 + lane * 2];
        float x0 = bflo(uv), x1 = bfhi(uv);
        float p;
        if (MODE == 0) {
            p = (x0 + x1) * 0.1f;
        } else {
            int j = row >> 4;
            float2 cc = *(const float2*)&c_sh[j * 128 + lane * 2];
            p = fmaf(x0, cc.x, x1 * cc.y);
        }
#pragma unroll
        for (int off = 32; off; off >>= 1) p += __shfl_down(p, off);
        if (lane == 0) atomicAdd(&s_glob[b * 160 + row], p);
    }
}

// ---------------- squash: s -> v (or out), re-zero s -------------------------------------
template <int LAST>
__global__ __launch_bounds__(192) void squash_k(float* __restrict__ s_glob,
                                                float* __restrict__ v_glob,
                                                float* __restrict__ out) {
    int b = blockIdx.x, tid = threadIdx.x;
    __shared__ float s_sh[160];
    __shared__ float sc[10];
    if (tid < 160) s_sh[tid] = s_glob[b * 160 + tid];
    __syncthreads();
    if (tid < 10) {
        float sq = 0.f;
#pragma unroll
        for (int q = 0; q < 16; q++) { float x = s_sh[tid * 16 + q]; sq += x * x; }
        float norm = sqrtf(sq + 1e-8f);
        sc[tid] = (sq / (1.0f + sq)) / norm;
    }
    __syncthreads();
    if (tid < 160) {
        float v = s_sh[tid] * sc[tid >> 4];
        if (LAST) out[b * 160 + tid] = v;
        else v_glob[b * 160 + tid] = v;
        s_glob[b * 160 + tid] = 0.f;
    }
}

extern "C" void kernel_launch(void* const* d_in, const int* in_sizes, int n_in,
                              void* d_out, int out_size, void* d_ws, size_t ws_size,
                              hipStream_t stream) {
    const float* input = (const float*)d_in[0];
    const float* c1w = (const float*)d_in[1];
    const float* c1b = (const float*)d_in[2];
    const float* c2w = (const float*)d_in[3];
    const float* c2b = (const float*)d_in[4];
    const float* capW = (const float*)d_in[5];
    float* out = (float*)d_out;

    // ws layout (bytes):
    //   [0)            u fp32 [512][9216]                      18,874,368
    //   [+18874368)    s_glob fp32 [512][160]                     327,680
    //   [+19202048)    v_glob fp32 [512][160]                     327,680
    //   [+19529728)    logits fp32 [512][10][1152]             23,592,960
    //                  (aliased: conv2 split-K part1, dead before routing t1)
    //   [+43122688)    region B: {Wt2 84 planes + h1n + part2,3} then uhat bf16 reuse
    const size_t U_OFF = 0;
    const size_t S_OFF = 18874368;
    const size_t V_OFF = 19202048;
    const size_t L_OFF = 19529728;
    const size_t B_OFF = 43122688;
    const size_t WT2_BYTES = (size_t)84 * 65536 * 2;       // 11,010,048
    const size_t H1N_BYTES = 104857600;
    const size_t PART_BYTES = (size_t)PART_FLOATS * 4;     // 18,874,368
    const size_t CONV_BYTES = WT2_BYTES + H1N_BYTES + 2 * PART_BYTES;  // 153.6 MB
    if (ws_size < B_OFF + CONV_BYTES) return;

    char* wsb = (char*)d_ws;
    float* u_buf = (float*)(wsb + U_OFF);
    float* s_glob = (float*)(wsb + S_OFF);
    float* v_glob = (float*)(wsb + V_OFF);
    float* logits = (float*)(wsb + L_OFF);
    float* part1  = (float*)(wsb + L_OFF);   // aliases logits (dead until routing t1)
    unsigned short* Wt2 = (unsigned short*)(wsb + B_OFF);
    unsigned short* h1n = (unsigned short*)(wsb + B_OFF + WT2_BYTES);
    float* part23 = (float*)(wsb + B_OFF + WT2_BYTES + H1N_BYTES);
    unsigned short* uhatb = (unsigned short*)(wsb + B_OFF);

    size_t availB = ws_size - B_OFF;
    int Cr = 0;
    const int cands[7] = {512, 256, 128, 64, 32, 16, 8};
    for (int k = 0; k < 7; k++) {
        if ((size_t)cands[k] * 368640 <= availB) { Cr = cands[k]; break; }
    }
    if (Cr == 0) return;

    zero_k<<<320, 256, 0, stream>>>(s_glob, 81920);
    wt2_k<<<256, 256, 0, stream>>>(c2w, Wt2);
    conv1_k<<<512 * 16, 320, 0, stream>>>(input, c1w, c1b, h1n);
    conv2_k<<<dim3(144, 2, 4), 256, 0, stream>>>(h1n, Wt2, c2b, u_buf, part1, part23);
    add_k<<<4608, 256, 0, stream>>>(u_buf, part1, part23);

    for (int b0 = 0; b0 < 512; b0 += Cr) {
        uhat_k<<<dim3(18, Cr / 8), 256, 0, stream>>>(u_buf + (size_t)b0 * 9216, capW, uhatb);
        routeAB_k<0><<<dim3(9, Cr), 256, 0, stream>>>(uhatb, v_glob, logits, s_glob);
        squash_k<0><<<Cr, 192, 0, stream>>>(s_glob, v_glob, out);
        routeAB_k<1><<<dim3(9, Cr), 256, 0, stream>>>(uhatb, v_glob, logits, s_glob);
        squash_k<0><<<Cr, 192, 0, stream>>>(s_glob, v_glob, out);
        routeAB_k<2><<<dim3(9, Cr), 256, 0, stream>>>(uhatb, v_glob, logits, s_glob);
        squash_k<1><<<Cr, 192, 0, stream>>>(s_glob, v_glob, out + (size_t)b0 * 160);
    }
}